// Round 11
// baseline (174.283 us; speedup 1.0000x reference)
//
#include <hip/hip_runtime.h>

#define BB 4
#define NN 2048
#define FF 128
#define ALPHA 0.2f
#define SHIFT_C 16.0f  // exp(x-16): x=LR(f1+f2) bounded ~|10|; masked entries -> p=0 via bit-multiply

typedef short bf16x8 __attribute__((ext_vector_type(8)));
typedef float f32x4 __attribute__((ext_vector_type(4)));

__device__ inline short f2bf(float f) {  // RNE float -> bf16 bits
    union { float f; unsigned u; } v; v.f = f;
    unsigned r = (v.u + 0x7FFFu + ((v.u >> 16) & 1u)) >> 16;
    return (short)r;
}
__device__ inline float bf2f(short s) {
    union { float f; unsigned u; } v;
    v.u = ((unsigned)(unsigned short)s) << 16;
    return v.f;
}

// ---------------------------------------------------------------------------
// k_pack (VERBATIM round 10, passed): adjp[i][w] = bitmask of adj row i.
// ---------------------------------------------------------------------------
__global__ __launch_bounds__(256) void k_pack(const int* __restrict__ adj,
                                              unsigned* __restrict__ adjp) {
    int w = threadIdx.x >> 6, lane = threadIdx.x & 63;
    int row = blockIdx.x * 4 + w;
    const int* ar = adj + (size_t)row * NN;
    for (int it = 0; it < 32; ++it) {
        int v = ar[it * 64 + lane];
        unsigned long long mask = __ballot(v > 0);
        if (lane == 0) adjp[row * 64 + it * 2] = (unsigned)mask;
        if (lane == 1) adjp[row * 64 + it * 2 + 1] = (unsigned)(mask >> 32);
    }
}

// ---------------------------------------------------------------------------
// k_wh (round-10 body, passed; stride back to UNPADDED NN = round-7 layout):
// fused f12 + fp32 GEMM + split-bf16 transposed store. 16 rows/block, grid 512.
// ---------------------------------------------------------------------------
__global__ __launch_bounds__(256) void k_wh(const float* __restrict__ h,
                                            const float* __restrict__ W,
                                            const float* __restrict__ a,
                                            short* __restrict__ WhHiT,
                                            short* __restrict__ WhLoT,
                                            float* __restrict__ f1,
                                            float* __restrict__ f2) {
    __shared__ float Wa[2 * FF];
    __shared__ float hs[16 * 128];  // 8 KB
    int tid = threadIdx.x;
    int r0 = blockIdx.x * 16;

    {
        int fin = tid & 127;
        const float* av = (tid < 128) ? a : (a + FF);
        const float* wr = W + (size_t)fin * FF;
        float s = 0.f;
        for (int o = 0; o < FF; o += 4) {
            float4 wv = *(const float4*)(wr + o);
            float4 avv = *(const float4*)(av + o);
            s += wv.x * avv.x + wv.y * avv.y + wv.z * avv.z + wv.w * avv.w;
        }
        Wa[(tid < 128 ? 0 : FF) + fin] = s;
    }
    {
        const float4* src = (const float4*)(h + (size_t)r0 * FF);
        float4* dst = (float4*)hs;
        dst[tid] = src[tid];
        dst[256 + tid] = src[256 + tid];
    }
    __syncthreads();

    {
        int w = tid >> 6, lane = tid & 63;
        float wa1_0 = Wa[lane], wa1_1 = Wa[lane + 64];
        float wa2_0 = Wa[FF + lane], wa2_1 = Wa[FF + lane + 64];
        for (int rr = 0; rr < 4; ++rr) {
            int rloc = w * 4 + rr;
            int row = r0 + rloc;
            float x0 = hs[rloc * FF + lane], x1 = hs[rloc * FF + lane + 64];
            float s1 = x0 * wa1_0 + x1 * wa1_1;
            float s2 = x0 * wa2_0 + x1 * wa2_1;
#pragma unroll
            for (int m = 32; m >= 1; m >>= 1) {
                s1 += __shfl_xor(s1, m, 64);
                s2 += __shfl_xor(s2, m, 64);
            }
            if (lane == 0) { f1[row] = s1; f2[row] = s2; }
        }
    }

    int f4 = (tid & 31) * 4;
    int rg = tid >> 5;  // 0..7
    float acc[2][4];
#pragma unroll
    for (int rr = 0; rr < 2; ++rr)
#pragma unroll
        for (int cc = 0; cc < 4; ++cc) acc[rr][cc] = 0.f;

    for (int k0 = 0; k0 < FF; k0 += 4) {
        float4 wv[4];
#pragma unroll
        for (int kk = 0; kk < 4; ++kk)
            wv[kk] = *(const float4*)(W + (size_t)(k0 + kk) * FF + f4);
        float4 hv[2];
#pragma unroll
        for (int rr = 0; rr < 2; ++rr)
            hv[rr] = *(const float4*)(hs + (rg * 2 + rr) * FF + k0);
#pragma unroll
        for (int rr = 0; rr < 2; ++rr) {
            float hk[4] = {hv[rr].x, hv[rr].y, hv[rr].z, hv[rr].w};
#pragma unroll
            for (int kk = 0; kk < 4; ++kk) {
                acc[rr][0] += hk[kk] * wv[kk].x;
                acc[rr][1] += hk[kk] * wv[kk].y;
                acc[rr][2] += hk[kk] * wv[kk].z;
                acc[rr][3] += hk[kk] * wv[kk].w;
            }
        }
    }
    int rloc = r0 + rg * 2;
    int b = rloc >> 11;
    int j = rloc & (NN - 1);  // even
#pragma unroll
    for (int cc = 0; cc < 4; ++cc) {
        float v0 = acc[0][cc], v1 = acc[1][cc];
        short h0 = f2bf(v0), h1 = f2bf(v1);
        short l0 = f2bf(v0 - bf2f(h0)), l1 = f2bf(v1 - bf2f(h1));
        size_t off = (size_t)(b * FF + f4 + cc) * NN + j;
        *(short2*)(WhHiT + off) = make_short2(h0, h1);
        *(short2*)(WhLoT + off) = make_short2(l0, l1);
    }
}

// ---------------------------------------------------------------------------
// k_attn: flash-GEMM. Block = 128 rows x full K (64 steps x 32 j), grid 64.
// 4 waves m-split (2 m-frags each). Per step the 16 KB B-tile (hi+lo,
// round-7 WhT layout) is staged into double-buffered LDS (loads issued one
// step ahead; 4 int4 loads + 4 ds_write_b128 per wave) and shared by all
// waves via ds_read_b128 with an octet-rotate swizzle. A (P~) built in regs
// from f1/f2/adjp. Exclusive output rows -> direct normalized store.
// LDS chunk(fo, slot c) holds j-octet (c+fo)&3 of step's 32-j range.
// ---------------------------------------------------------------------------
__global__ __launch_bounds__(256, 1) void k_attn(const short* __restrict__ WhHiT,
                                                 const short* __restrict__ WhLoT,
                                                 const unsigned* __restrict__ adjp,
                                                 const float* __restrict__ f1,
                                                 const float* __restrict__ f2,
                                                 float* __restrict__ out) {
    __shared__ int4 ldsb[2048];      // 32 KB: 2 bufs x (8 KB hi + 8 KB lo)
    __shared__ float row_s[4][32];
    char* lds = (char*)ldsb;

    int tid = threadIdx.x;
    int w = tid >> 6, lane = tid & 63;
    int r_a = lane & 15, kg = lane >> 4;

    int mt = blockIdx.x;         // 0..63
    int b = mt >> 4;
    int i0 = (mt & 15) * 128;    // batch-local row base

    int iloc0 = i0 + w * 32 + r_a;   // m-frag 0 row (batch-local)
    int iloc1 = iloc0 + 16;          // m-frag 1 row
    float f1_0 = f1[b * NN + iloc0];
    float f1_1 = f1[b * NN + iloc1];
    const float* f2b = f2 + b * NN;
    const unsigned* ap0 = adjp + (size_t)iloc0 * 64;
    const unsigned* ap1 = adjp + (size_t)iloc1 * 64;

    // staging constants: wave w owns slots {w, w+4} of hi and lo
    int t0 = w, t1 = w + 4;
    int fo0 = t0 * 16 + (lane >> 2), fo1 = t1 * 16 + (lane >> 2);
    int oc0 = ((lane & 3) + fo0) & 3, oc1 = ((lane & 3) + fo1) & 3;
    const short* gh0 = WhHiT + (size_t)(b * FF + fo0) * NN + oc0 * 8;
    const short* gh1 = WhHiT + (size_t)(b * FF + fo1) * NN + oc1 * 8;
    const short* gl0 = WhLoT + (size_t)(b * FF + fo0) * NN + oc0 * 8;
    const short* gl1 = WhLoT + (size_t)(b * FF + fo1) * NN + oc1 * 8;
    int d0 = t0 * 1024 + lane * 16;  // lds dest offsets within a buffer
    int d1 = t1 * 1024 + lane * 16;
    int rdo = r_a * 64 + ((kg - r_a) & 3) * 16;  // read-frag lane offset

    f32x4 acc0[8], acc1[8];
#pragma unroll
    for (int n = 0; n < 8; ++n)
#pragma unroll
        for (int q = 0; q < 4; ++q) { acc0[n][q] = 0.f; acc1[n][q] = 0.f; }
    float sp0 = 0.f, sp1 = 0.f;

    // ---- prologue: stage step 0 -> buf0; issue loads for step 1 ----
    {
        int4 h0 = *(const int4*)(gh0);
        int4 h1 = *(const int4*)(gh1);
        int4 l0 = *(const int4*)(gl0);
        int4 l1 = *(const int4*)(gl1);
        *(int4*)(lds + d0) = h0;
        *(int4*)(lds + d1) = h1;
        *(int4*)(lds + 8192 + d0) = l0;
        *(int4*)(lds + 8192 + d1) = l1;
    }
    int4 sh0 = *(const int4*)(gh0 + 32);
    int4 sh1 = *(const int4*)(gh1 + 32);
    int4 sl0 = *(const int4*)(gl0 + 32);
    int4 sl1 = *(const int4*)(gl1 + 32);
    float4 pq0 = *(const float4*)(f2b + kg * 8);
    float4 pq1 = *(const float4*)(f2b + kg * 8 + 4);
    unsigned pw0 = ap0[0], pw1 = ap1[0];
    __syncthreads();

    for (int s = 0; s < 64; ++s) {
        // write buf[(s+1)&1] with staged regs (step s+1 data)
        char* wb = lds + ((s + 1) & 1) * 16384;
        *(int4*)(wb + d0) = sh0;
        *(int4*)(wb + d1) = sh1;
        *(int4*)(wb + 8192 + d0) = sl0;
        *(int4*)(wb + 8192 + d1) = sl1;
        // issue loads for step s+2 (wrapped; wrap data unused)
        int kn = ((s + 2) & 63) * 32;
        sh0 = *(const int4*)(gh0 + kn);
        sh1 = *(const int4*)(gh1 + kn);
        sl0 = *(const int4*)(gl0 + kn);
        sl1 = *(const int4*)(gl1 + kn);

        // A-build for step s (prefetched regs)
        float qv[8] = {pq0.x, pq0.y, pq0.z, pq0.w, pq1.x, pq1.y, pq1.z, pq1.w};
        unsigned w0 = pw0 >> (kg * 8), w1 = pw1 >> (kg * 8);
        bf16x8 af0, af1;
#pragma unroll
        for (int t = 0; t < 8; ++t) {
            float q = qv[t];
            float b0 = (float)((w0 >> t) & 1u);
            float b1 = (float)((w1 >> t) & 1u);
            float x0 = f1_0 + q, x1 = f1_1 + q;
            x0 = fmaxf(x0, ALPHA * x0);           // leaky-relu via max (alpha<1)
            x1 = fmaxf(x1, ALPHA * x1);
            float p0 = __expf(x0 - SHIFT_C) * b0; // masked -> exactly 0
            float p1 = __expf(x1 - SHIFT_C) * b1;
            sp0 += p0; sp1 += p1;
            union { float f; unsigned u; } u0, u1; u0.f = p0; u1.f = p1;
            af0[t] = (short)((u0.u + 0x8000u) >> 16);  // round-half-up bf16
            af1[t] = (short)((u1.u + 0x8000u) >> 16);
        }
        // prefetch A data for step s+1 (wrapped)
        int sn = (s + 1) & 63;
        pq0 = *(const float4*)(f2b + sn * 32 + kg * 8);
        pq1 = *(const float4*)(f2b + sn * 32 + kg * 8 + 4);
        pw0 = ap0[sn]; pw1 = ap1[sn];

        // MFMAs against buf[s&1]
        char* rb = lds + (s & 1) * 16384;
#pragma unroll
        for (int n = 0; n < 8; ++n) {
            bf16x8 fh = *(const bf16x8*)(rb + n * 1024 + rdo);
            bf16x8 fl = *(const bf16x8*)(rb + 8192 + n * 1024 + rdo);
            acc0[n] = __builtin_amdgcn_mfma_f32_16x16x32_bf16(af0, fh, acc0[n], 0, 0, 0);
            acc0[n] = __builtin_amdgcn_mfma_f32_16x16x32_bf16(af0, fl, acc0[n], 0, 0, 0);
            acc1[n] = __builtin_amdgcn_mfma_f32_16x16x32_bf16(af1, fh, acc1[n], 0, 0, 0);
            acc1[n] = __builtin_amdgcn_mfma_f32_16x16x32_bf16(af1, fl, acc1[n], 0, 0, 0);
        }
        __syncthreads();
    }

    // ---- row sums (kg replicas) -> LDS broadcast ----
    sp0 += __shfl_xor(sp0, 16, 64); sp0 += __shfl_xor(sp0, 32, 64);
    sp1 += __shfl_xor(sp1, 16, 64); sp1 += __shfl_xor(sp1, 32, 64);
    if (lane < 16) { row_s[w][r_a] = sp0; row_s[w][16 + r_a] = sp1; }
    __syncthreads();

    // ---- normalized direct store: row kg*4+q, col n*16+r_a (C layout) ----
    float* ob = out + ((size_t)b * NN + i0 + w * 32) * FF;
#pragma unroll
    for (int q = 0; q < 4; ++q) {
        float inv_0 = 1.0f / row_s[w][kg * 4 + q];
        float inv_1 = 1.0f / row_s[w][16 + kg * 4 + q];
#pragma unroll
        for (int n = 0; n < 8; ++n) {
            ob[(size_t)(kg * 4 + q) * FF + n * 16 + r_a] = acc0[n][q] * inv_0;
            ob[(size_t)(16 + kg * 4 + q) * FF + n * 16 + r_a] = acc1[n][q] * inv_1;
        }
    }
}

// ---------------------------------------------------------------------------
extern "C" void kernel_launch(void* const* d_in, const int* in_sizes, int n_in,
                              void* d_out, int out_size, void* d_ws, size_t ws_size,
                              hipStream_t stream) {
    const float* h   = (const float*)d_in[0];
    const int*   adj = (const int*)d_in[1];
    const float* W   = (const float*)d_in[2];
    const float* a   = (const float*)d_in[3];
    float* out = (float*)d_out;

    short* WhHiT = (short*)d_ws;                          // 2 MB
    short* WhLoT = WhHiT + (size_t)BB * FF * NN;          // 2 MB
    float* f1 = (float*)(WhLoT + (size_t)BB * FF * NN);   // 32 KB
    float* f2 = f1 + (size_t)BB * NN;                     // 32 KB
    unsigned* adjp = (unsigned*)(f2 + (size_t)BB * NN);   // 512 KB (total 4.63 MB)

    k_pack<<<NN / 4, 256, 0, stream>>>(adj, adjp);
    k_wh<<<(BB * NN) / 16, 256, 0, stream>>>(h, W, a, WhHiT, WhLoT, f1, f2);
    k_attn<<<64, 256, 0, stream>>>(WhHiT, WhLoT, adjp, f1, f2, out);
}

// Round 12
// 149.830 us; speedup vs baseline: 1.1632x; 1.1632x over previous
//
#include <hip/hip_runtime.h>

#define BB 4
#define NN 2048
#define FF 128
#define ALPHA 0.2f
#define SHIFT_C 16.0f  // exp(x-16): x=LR(f1+f2) bounded ~|10|; masked -> p=0 via bit-multiply

typedef short bf16x8 __attribute__((ext_vector_type(8)));
typedef short bf16x4 __attribute__((ext_vector_type(4)));
typedef float f32x4 __attribute__((ext_vector_type(4)));
typedef unsigned u32;

__device__ inline short f2bf(float f) {  // RNE float -> bf16 bits
    union { float f; unsigned u; } v; v.f = f;
    unsigned r = (v.u + 0x7FFFu + ((v.u >> 16) & 1u)) >> 16;
    return (short)r;
}
__device__ inline float bf2f(short s) {
    union { float f; unsigned u; } v;
    v.u = ((unsigned)(unsigned short)s) << 16;
    return v.f;
}

// async 16B global->LDS (gfx950); lds dest must be wave-uniform base (+lane*16)
__device__ inline void cp16(const void* g, void* l) {
    __builtin_amdgcn_global_load_lds(
        (const __attribute__((address_space(1))) u32*)g,
        (__attribute__((address_space(3))) u32*)l, 16, 0, 0);
}

// ---------------------------------------------------------------------------
// k_wh: round-11 body (passed) + folded adj bit-packing (4 rows/block).
// Fused f12 + fp32 GEMM + split-bf16 transposed store (stride NN). Grid 512.
// ---------------------------------------------------------------------------
__global__ __launch_bounds__(256) void k_wh(const float* __restrict__ h,
                                            const float* __restrict__ W,
                                            const float* __restrict__ a,
                                            const int* __restrict__ adj,
                                            short* __restrict__ WhHiT,
                                            short* __restrict__ WhLoT,
                                            float* __restrict__ f1,
                                            float* __restrict__ f2,
                                            u32* __restrict__ adjp) {
    __shared__ float Wa[2 * FF];
    __shared__ float hs[16 * 128];  // 8 KB
    int tid = threadIdx.x;
    int r0 = blockIdx.x * 16;

    {
        int fin = tid & 127;
        const float* av = (tid < 128) ? a : (a + FF);
        const float* wr = W + (size_t)fin * FF;
        float s = 0.f;
        for (int o = 0; o < FF; o += 4) {
            float4 wv = *(const float4*)(wr + o);
            float4 avv = *(const float4*)(av + o);
            s += wv.x * avv.x + wv.y * avv.y + wv.z * avv.z + wv.w * avv.w;
        }
        Wa[(tid < 128 ? 0 : FF) + fin] = s;
    }
    {
        const float4* src = (const float4*)(h + (size_t)r0 * FF);
        float4* dst = (float4*)hs;
        dst[tid] = src[tid];
        dst[256 + tid] = src[256 + tid];
    }
    // ---- folded adj packing: wave w packs adj row blockIdx*4 + w ----
    {
        int w = tid >> 6, lane = tid & 63;
        int row = blockIdx.x * 4 + w;  // 512 blocks * 4 = 2048 rows
        const int* ar = adj + (size_t)row * NN;
        for (int it = 0; it < 32; ++it) {
            int v = ar[it * 64 + lane];
            unsigned long long mask = __ballot(v > 0);
            if (lane == 0) adjp[row * 64 + it * 2] = (u32)mask;
            if (lane == 1) adjp[row * 64 + it * 2 + 1] = (u32)(mask >> 32);
        }
    }
    __syncthreads();

    {
        int w = tid >> 6, lane = tid & 63;
        float wa1_0 = Wa[lane], wa1_1 = Wa[lane + 64];
        float wa2_0 = Wa[FF + lane], wa2_1 = Wa[FF + lane + 64];
        for (int rr = 0; rr < 4; ++rr) {
            int rloc = w * 4 + rr;
            int row = r0 + rloc;
            float x0 = hs[rloc * FF + lane], x1 = hs[rloc * FF + lane + 64];
            float s1 = x0 * wa1_0 + x1 * wa1_1;
            float s2 = x0 * wa2_0 + x1 * wa2_1;
#pragma unroll
            for (int m = 32; m >= 1; m >>= 1) {
                s1 += __shfl_xor(s1, m, 64);
                s2 += __shfl_xor(s2, m, 64);
            }
            if (lane == 0) { f1[row] = s1; f2[row] = s2; }
        }
    }

    int f4 = (tid & 31) * 4;
    int rg = tid >> 5;  // 0..7
    float acc[2][4];
#pragma unroll
    for (int rr = 0; rr < 2; ++rr)
#pragma unroll
        for (int cc = 0; cc < 4; ++cc) acc[rr][cc] = 0.f;

    for (int k0 = 0; k0 < FF; k0 += 4) {
        float4 wv[4];
#pragma unroll
        for (int kk = 0; kk < 4; ++kk)
            wv[kk] = *(const float4*)(W + (size_t)(k0 + kk) * FF + f4);
        float4 hv[2];
#pragma unroll
        for (int rr = 0; rr < 2; ++rr)
            hv[rr] = *(const float4*)(hs + (rg * 2 + rr) * FF + k0);
#pragma unroll
        for (int rr = 0; rr < 2; ++rr) {
            float hk[4] = {hv[rr].x, hv[rr].y, hv[rr].z, hv[rr].w};
#pragma unroll
            for (int kk = 0; kk < 4; ++kk) {
                acc[rr][0] += hk[kk] * wv[kk].x;
                acc[rr][1] += hk[kk] * wv[kk].y;
                acc[rr][2] += hk[kk] * wv[kk].z;
                acc[rr][3] += hk[kk] * wv[kk].w;
            }
        }
    }
    int rloc = r0 + rg * 2;
    int b = rloc >> 11;
    int j = rloc & (NN - 1);  // even
#pragma unroll
    for (int cc = 0; cc < 4; ++cc) {
        float v0 = acc[0][cc], v1 = acc[1][cc];
        short h0 = f2bf(v0), h1 = f2bf(v1);
        short l0 = f2bf(v0 - bf2f(h0)), l1 = f2bf(v1 - bf2f(h1));
        size_t off = (size_t)(b * FF + f4 + cc) * NN + j;
        *(short2*)(WhHiT + off) = make_short2(h0, h1);
        *(short2*)(WhLoT + off) = make_short2(l0, l1);
    }
}

// ---------------------------------------------------------------------------
// k_attn flash-v2: grid 256 (1 block/CU), 512 thr (8 waves = 2/SIMD).
// Block = 32 rows x full K (64 steps x 32 j). Per step:
//  - B-tile (32j x 128fo, hi+lo, 16 KB) via async global_load_lds, dbuf
//  - A-tile (32x32 P~) built cooperatively (2 p/thread) into padded LDS, dbuf
//  - wave (mi,ni): 1 A ds_read + 4 B ds_reads + 4 MFMA
// One barrier/step (drains own async loads + LDS writes). Direct norm store.
// ---------------------------------------------------------------------------
__global__ __launch_bounds__(512, 2) void k_attn(const short* __restrict__ WhHiT,
                                                 const short* __restrict__ WhLoT,
                                                 const u32* __restrict__ adjp,
                                                 const float* __restrict__ f1,
                                                 const float* __restrict__ f2,
                                                 float* __restrict__ out) {
    __shared__ __align__(16) char lds[39040];
    char* B0 = lds;                           // 2 x 16384 (hi 8K + lo 8K each)
    char* A0 = lds + 32768;                   // 2 x 2560 (2 mi x 16 rows x 80 B)
    float* row_ps = (float*)(lds + 37888);    // [8][32]
    float* row_inv = (float*)(lds + 38912);   // [32]

    int tid = threadIdx.x;
    int w = tid >> 6, lane = tid & 63;
    int blk = blockIdx.x;
    int b = blk >> 6;
    int i0 = (blk & 63) * 32;

    // compute roles
    int r_a = lane & 15, kg = lane >> 4;
    int mi = w >> 2, ni = w & 3;

    // A-build role: thread -> (row rb, j-pair jp)
    int rb = tid & 31;
    int jp = tid >> 5;  // 0..15
    float f1i = f1[b * NN + i0 + rb];
    const u32* aprow = adjp + (size_t)(i0 + rb) * 64;
    const float* f2b = f2 + b * NN;
    int aoff = (rb >> 4) * 1280 + (rb & 15) * 80 + jp * 4;

    // B-stage role: wave w stages fo in [w*16, w*16+16), hi & lo
    int fo_s = w * 16 + (lane >> 2);
    int oc_s = lane & 3;
    const short* gH = WhHiT + (size_t)(b * FF + fo_s) * NN + oc_s * 8;
    const short* gL = WhLoT + (size_t)(b * FF + fo_s) * NN + oc_s * 8;
    int bH = w * 1024;         // wave-uniform LDS issue bases
    int bL = 8192 + w * 1024;

    f32x4 acc0 = {0.f, 0.f, 0.f, 0.f}, acc1 = {0.f, 0.f, 0.f, 0.f};
    float sp = 0.f;

    // ---- prologue: B(0)->buf0 async; A(0)->Abuf0; prefetch step-1 regs ----
    cp16(gH, B0 + bH);
    cp16(gL, B0 + bL);
    {
        float2 q = *(const float2*)(f2b + jp * 2);
        u32 mw = aprow[0];
        float x0 = f1i + q.x, x1 = f1i + q.y;
        x0 = fmaxf(x0, ALPHA * x0);
        x1 = fmaxf(x1, ALPHA * x1);
        float p0 = __expf(x0 - SHIFT_C) * (float)((mw >> (jp * 2)) & 1u);
        float p1 = __expf(x1 - SHIFT_C) * (float)((mw >> (jp * 2 + 1)) & 1u);
        sp += p0 + p1;
        union { float f; u32 u; } u0, u1; u0.f = p0; u1.f = p1;
        *(u32*)(A0 + aoff) = ((u0.u + 0x8000u) >> 16) | (((u1.u + 0x8000u) >> 16) << 16);
    }
    float2 pf2 = *(const float2*)(f2b + 32 + jp * 2);
    u32 pmw = aprow[1];
    __syncthreads();

    for (int s = 0; s < 64; ++s) {
        // issue B(s+1) async (wrapped at s=63; wrap data unread)
        {
            int jn = ((s + 1) & 63) * 32;
            char* wb = B0 + ((s + 1) & 1) * 16384;
            cp16(gH + jn, wb + bH);
            cp16(gL + jn, wb + bL);
        }
        // build A(s+1) from prefetched regs
        {
            char* wa = A0 + ((s + 1) & 1) * 2560;
            float x0 = f1i + pf2.x, x1 = f1i + pf2.y;
            x0 = fmaxf(x0, ALPHA * x0);
            x1 = fmaxf(x1, ALPHA * x1);
            float p0 = __expf(x0 - SHIFT_C) * (float)((pmw >> (jp * 2)) & 1u);
            float p1 = __expf(x1 - SHIFT_C) * (float)((pmw >> (jp * 2 + 1)) & 1u);
            if (s < 63) sp += p0 + p1;  // exclude wrapped rebuild of step 0
            union { float f; u32 u; } u0, u1; u0.f = p0; u1.f = p1;
            *(u32*)(wa + aoff) = ((u0.u + 0x8000u) >> 16) | (((u1.u + 0x8000u) >> 16) << 16);
        }
        // prefetch regs for s+2 (wrapped)
        {
            int sn = (s + 2) & 63;
            pf2 = *(const float2*)(f2b + sn * 32 + jp * 2);
            pmw = aprow[sn];
        }
        // compute step s
        {
            char* rbuf = B0 + (s & 1) * 16384;
            char* abuf = A0 + (s & 1) * 2560;
            bf16x8 af = *(const bf16x8*)(abuf + mi * 1280 + r_a * 80 + kg * 16);
            int n0 = ni * 2;
            const char* p0 = rbuf + ((n0 * 16 + r_a) * 64 + kg * 16);
            const char* p1 = rbuf + (((n0 + 1) * 16 + r_a) * 64 + kg * 16);
            bf16x8 b0h = *(const bf16x8*)p0;
            bf16x8 b0l = *(const bf16x8*)(p0 + 8192);
            bf16x8 b1h = *(const bf16x8*)p1;
            bf16x8 b1l = *(const bf16x8*)(p1 + 8192);
            acc0 = __builtin_amdgcn_mfma_f32_16x16x32_bf16(af, b0h, acc0, 0, 0, 0);
            acc0 = __builtin_amdgcn_mfma_f32_16x16x32_bf16(af, b0l, acc0, 0, 0, 0);
            acc1 = __builtin_amdgcn_mfma_f32_16x16x32_bf16(af, b1h, acc1, 0, 0, 0);
            acc1 = __builtin_amdgcn_mfma_f32_16x16x32_bf16(af, b1l, acc1, 0, 0, 0);
        }
        __syncthreads();
    }

    // ---- row sums: thread covers (row rb, its 2 jp-cols over all steps) ----
    sp += __shfl_xor(sp, 32, 64);              // pair jp, jp^1 (same row)
    if (lane < 32) row_ps[w * 32 + lane] = sp; // lane == its row for lane<32
    __syncthreads();
    if (tid < 32) {
        float t = 0.f;
#pragma unroll
        for (int ww = 0; ww < 8; ++ww) t += row_ps[ww * 32 + tid];
        row_inv[tid] = 1.0f / t;
    }
    __syncthreads();

    // ---- direct normalized store: wave (mi,ni) owns rows mi*16+.., fo ni*32+.. ----
    float* ob = out + ((size_t)b * NN + i0 + mi * 16) * FF + ni * 32;
#pragma unroll
    for (int q = 0; q < 4; ++q) {
        int rr = kg * 4 + q;
        float inv = row_inv[mi * 16 + rr];
        ob[(size_t)rr * FF + r_a] = acc0[q] * inv;
        ob[(size_t)rr * FF + 16 + r_a] = acc1[q] * inv;
    }
}

// ---------------------------------------------------------------------------
extern "C" void kernel_launch(void* const* d_in, const int* in_sizes, int n_in,
                              void* d_out, int out_size, void* d_ws, size_t ws_size,
                              hipStream_t stream) {
    const float* h   = (const float*)d_in[0];
    const int*   adj = (const int*)d_in[1];
    const float* W   = (const float*)d_in[2];
    const float* a   = (const float*)d_in[3];
    float* out = (float*)d_out;

    short* WhHiT = (short*)d_ws;                          // 2 MB
    short* WhLoT = WhHiT + (size_t)BB * FF * NN;          // 2 MB
    float* f1 = (float*)(WhLoT + (size_t)BB * FF * NN);   // 32 KB
    float* f2 = f1 + (size_t)BB * NN;                     // 32 KB
    u32* adjp = (u32*)(f2 + (size_t)BB * NN);             // 512 KB (total 4.63 MB, proven)

    k_wh<<<(BB * NN) / 16, 256, 0, stream>>>(h, W, a, adj, WhHiT, WhLoT, f1, f2, adjp);
    k_attn<<<BB * (NN / 32), 512, 0, stream>>>(WhHiT, WhLoT, adjp, f1, f2, out);
}

// Round 14
// 149.076 us; speedup vs baseline: 1.1691x; 1.0051x over previous
//
#include <hip/hip_runtime.h>

#define BB 4
#define NN 2048
#define FF 128
#define NP 2176  // padded WhT row stride (shorts): 4352 B = 17*256 -> L2 channel step 1
#define ALPHA 0.2f
#define SHIFT_C 16.0f  // exp(x-16): x=LR(f1+f2) bounded ~|10|; masked -> p=0 via bit-multiply

typedef short bf16x8 __attribute__((ext_vector_type(8)));
typedef float f32x4 __attribute__((ext_vector_type(4)));
typedef unsigned u32;

__device__ inline short f2bf(float f) {  // RNE float -> bf16 bits
    union { float f; unsigned u; } v; v.f = f;
    unsigned r = (v.u + 0x7FFFu + ((v.u >> 16) & 1u)) >> 16;
    return (short)r;
}
__device__ inline float bf2f(short s) {
    union { float f; unsigned u; } v;
    v.u = ((unsigned)(unsigned short)s) << 16;
    return v.f;
}

// async 16B global->LDS (gfx950); lds dest = wave-uniform base + lane*16
__device__ inline void cp16(const void* g, void* l) {
    __builtin_amdgcn_global_load_lds(
        (const __attribute__((address_space(1))) u32*)g,
        (__attribute__((address_space(3))) u32*)l, 16, 0, 0);
}

// ---------------------------------------------------------------------------
// k_wh: round-12 body (passed) with round-10's NP-padded store (passed).
// Fused f12 + adj-pack + fp32 GEMM + split-bf16 transposed store (stride NP).
// 16 rows/block, grid 512.
// ---------------------------------------------------------------------------
__global__ __launch_bounds__(256) void k_wh(const float* __restrict__ h,
                                            const float* __restrict__ W,
                                            const float* __restrict__ a,
                                            const int* __restrict__ adj,
                                            short* __restrict__ WhHiT,
                                            short* __restrict__ WhLoT,
                                            float* __restrict__ f1,
                                            float* __restrict__ f2,
                                            u32* __restrict__ adjp) {
    __shared__ float Wa[2 * FF];
    __shared__ float hs[16 * 128];  // 8 KB
    int tid = threadIdx.x;
    int r0 = blockIdx.x * 16;

    {
        int fin = tid & 127;
        const float* av = (tid < 128) ? a : (a + FF);
        const float* wr = W + (size_t)fin * FF;
        float s = 0.f;
        for (int o = 0; o < FF; o += 4) {
            float4 wv = *(const float4*)(wr + o);
            float4 avv = *(const float4*)(av + o);
            s += wv.x * avv.x + wv.y * avv.y + wv.z * avv.z + wv.w * avv.w;
        }
        Wa[(tid < 128 ? 0 : FF) + fin] = s;
    }
    {
        const float4* src = (const float4*)(h + (size_t)r0 * FF);
        float4* dst = (float4*)hs;
        dst[tid] = src[tid];
        dst[256 + tid] = src[256 + tid];
    }
    // folded adj packing: wave w packs adj row blockIdx*4 + w
    {
        int w = tid >> 6, lane = tid & 63;
        int row = blockIdx.x * 4 + w;
        const int* ar = adj + (size_t)row * NN;
        for (int it = 0; it < 32; ++it) {
            int v = ar[it * 64 + lane];
            unsigned long long mask = __ballot(v > 0);
            if (lane == 0) adjp[row * 64 + it * 2] = (u32)mask;
            if (lane == 1) adjp[row * 64 + it * 2 + 1] = (u32)(mask >> 32);
        }
    }
    __syncthreads();

    {
        int w = tid >> 6, lane = tid & 63;
        float wa1_0 = Wa[lane], wa1_1 = Wa[lane + 64];
        float wa2_0 = Wa[FF + lane], wa2_1 = Wa[FF + lane + 64];
        for (int rr = 0; rr < 4; ++rr) {
            int rloc = w * 4 + rr;
            int row = r0 + rloc;
            float x0 = hs[rloc * FF + lane], x1 = hs[rloc * FF + lane + 64];
            float s1 = x0 * wa1_0 + x1 * wa1_1;
            float s2 = x0 * wa2_0 + x1 * wa2_1;
#pragma unroll
            for (int m = 32; m >= 1; m >>= 1) {
                s1 += __shfl_xor(s1, m, 64);
                s2 += __shfl_xor(s2, m, 64);
            }
            if (lane == 0) { f1[row] = s1; f2[row] = s2; }
        }
    }

    int f4 = (tid & 31) * 4;
    int rg = tid >> 5;  // 0..7
    float acc[2][4];
#pragma unroll
    for (int rr = 0; rr < 2; ++rr)
#pragma unroll
        for (int cc = 0; cc < 4; ++cc) acc[rr][cc] = 0.f;

    for (int k0 = 0; k0 < FF; k0 += 4) {
        float4 wv[4];
#pragma unroll
        for (int kk = 0; kk < 4; ++kk)
            wv[kk] = *(const float4*)(W + (size_t)(k0 + kk) * FF + f4);
        float4 hv[2];
#pragma unroll
        for (int rr = 0; rr < 2; ++rr)
            hv[rr] = *(const float4*)(hs + (rg * 2 + rr) * FF + k0);
#pragma unroll
        for (int rr = 0; rr < 2; ++rr) {
            float hk[4] = {hv[rr].x, hv[rr].y, hv[rr].z, hv[rr].w};
#pragma unroll
            for (int kk = 0; kk < 4; ++kk) {
                acc[rr][0] += hk[kk] * wv[kk].x;
                acc[rr][1] += hk[kk] * wv[kk].y;
                acc[rr][2] += hk[kk] * wv[kk].z;
                acc[rr][3] += hk[kk] * wv[kk].w;
            }
        }
    }
    int rloc = r0 + rg * 2;
    int b = rloc >> 11;
    int j = rloc & (NN - 1);  // even
#pragma unroll
    for (int cc = 0; cc < 4; ++cc) {
        float v0 = acc[0][cc], v1 = acc[1][cc];
        short h0 = f2bf(v0), h1 = f2bf(v1);
        short l0 = f2bf(v0 - bf2f(h0)), l1 = f2bf(v1 - bf2f(h1));
        size_t off = (size_t)(b * FF + f4 + cc) * NP + j;
        *(short2*)(WhHiT + off) = make_short2(h0, h1);
        *(short2*)(WhLoT + off) = make_short2(l0, l1);
    }
}

// ---------------------------------------------------------------------------
// k_attn flash-v4: round-13 roles (16 waves, 1024 thr, grid 256) with
// (a) TRIPLE-buffered B (async cp16 target is always >= 2 barriers from its
//     last reader -> immune to one-barrier scheduler hoists),
// (b) NP-padded WhT reads (B-tile rows spread over 16 L2 channels),
// (c) no unroll pragma.
// ---------------------------------------------------------------------------
__global__ __launch_bounds__(1024, 4) void k_attn(const short* __restrict__ WhHiT,
                                                  const short* __restrict__ WhLoT,
                                                  const u32* __restrict__ adjp,
                                                  const float* __restrict__ f1,
                                                  const float* __restrict__ f2,
                                                  float* __restrict__ out) {
    __shared__ __align__(16) char lds[55424];
    char* Bbuf = lds;                         // 3 x 16384 (hi 8K + lo 8K each)
    char* A0 = lds + 49152;                   // 2 x 2560 (2 mi x 16 rows x 80 B)
    float* row_ps = (float*)(lds + 54272);    // [8][32]
    float* row_inv = (float*)(lds + 55296);   // [32]

    int tid = threadIdx.x;
    int w = tid >> 6, lane = tid & 63;       // w in 0..15
    int blk = blockIdx.x;
    int b = blk >> 6;
    int i0 = (blk & 63) * 32;

    int r_a = lane & 15, kg = lane >> 4;
    int mi = w >> 3, ni = w & 7;

    // A-build role (tid < 512 only): thread -> (row rb, j-pair jp)
    int rb = tid & 31;
    int jp = (tid >> 5) & 15;
    bool abuild = tid < 512;
    float f1i = abuild ? f1[b * NN + i0 + rb] : 0.f;
    const u32* aprow = adjp + (size_t)(i0 + rb) * 64;
    const float* f2b = f2 + b * NN;
    int aoff = (rb >> 4) * 1280 + (rb & 15) * 80 + jp * 4;

    // B-stage role: wave w stages fo [hw*16..+16) of (w<8 ? hi : lo)
    int hw = w & 7;
    int isLo = w >> 3;
    int fo_s = hw * 16 + (lane >> 2);
    int oc_s = lane & 3;
    const short* gB = (isLo ? WhLoT : WhHiT) + (size_t)(b * FF + fo_s) * NP + oc_s * 8;
    int bB = isLo * 8192 + hw * 1024;  // wave-uniform LDS issue base

    f32x4 acc = {0.f, 0.f, 0.f, 0.f};
    float sp = 0.f;

    // ---- prologue: B(0) -> Bbuf[0] async; A(0) -> Abuf0; prefetch step-1 ----
    cp16(gB, Bbuf + bB);
    float2 pf2 = {0.f, 0.f};
    u32 pmw = 0;
    if (abuild) {
        float2 q = *(const float2*)(f2b + jp * 2);
        u32 mw = aprow[0];
        float x0 = f1i + q.x, x1 = f1i + q.y;
        x0 = fmaxf(x0, ALPHA * x0);
        x1 = fmaxf(x1, ALPHA * x1);
        float p0 = __expf(x0 - SHIFT_C) * (float)((mw >> (jp * 2)) & 1u);
        float p1 = __expf(x1 - SHIFT_C) * (float)((mw >> (jp * 2 + 1)) & 1u);
        sp += p0 + p1;
        union { float f; u32 u; } u0, u1; u0.f = p0; u1.f = p1;
        *(u32*)(A0 + aoff) = ((u0.u + 0x8000u) >> 16) | (((u1.u + 0x8000u) >> 16) << 16);
        pf2 = *(const float2*)(f2b + 32 + jp * 2);
        pmw = aprow[1];
    }
    __syncthreads();

    int cur = 0, nxt = 1;
    for (int s = 0; s < 64; ++s) {
        // issue B(s+1) async into Bbuf[nxt] (wrapped at s=63; wrap unread)
        {
            int jn = ((s + 1) & 63) * 32;
            cp16(gB + jn, Bbuf + nxt * 16384 + bB);
        }
        // build A(s+1) from prefetched regs
        if (abuild) {
            char* wa = A0 + ((s + 1) & 1) * 2560;
            float x0 = f1i + pf2.x, x1 = f1i + pf2.y;
            x0 = fmaxf(x0, ALPHA * x0);
            x1 = fmaxf(x1, ALPHA * x1);
            float p0 = __expf(x0 - SHIFT_C) * (float)((pmw >> (jp * 2)) & 1u);
            float p1 = __expf(x1 - SHIFT_C) * (float)((pmw >> (jp * 2 + 1)) & 1u);
            if (s < 63) sp += p0 + p1;  // exclude wrapped rebuild of step 0
            union { float f; u32 u; } u0, u1; u0.f = p0; u1.f = p1;
            *(u32*)(wa + aoff) = ((u0.u + 0x8000u) >> 16) | (((u1.u + 0x8000u) >> 16) << 16);
            int sn = (s + 2) & 63;
            pf2 = *(const float2*)(f2b + sn * 32 + jp * 2);
            pmw = aprow[sn];
        }
        // compute step s from Bbuf[cur] / Abuf[s&1]
        {
            char* rbuf = Bbuf + cur * 16384;
            char* abuf = A0 + (s & 1) * 2560;
            bf16x8 af = *(const bf16x8*)(abuf + mi * 1280 + r_a * 80 + kg * 16);
            const char* p = rbuf + ((ni * 16 + r_a) * 64 + kg * 16);
            bf16x8 bh = *(const bf16x8*)p;
            bf16x8 bl = *(const bf16x8*)(p + 8192);
            acc = __builtin_amdgcn_mfma_f32_16x16x32_bf16(af, bh, acc, 0, 0, 0);
            acc = __builtin_amdgcn_mfma_f32_16x16x32_bf16(af, bl, acc, 0, 0, 0);
        }
        __syncthreads();
        cur = nxt;
        nxt = (nxt == 2) ? 0 : nxt + 1;
    }

    // ---- row sums (waves 0..7 hold A partials) ----
    sp += __shfl_xor(sp, 32, 64);              // pair jp, jp^1 (same row rb)
    if (w < 8 && lane < 32) row_ps[w * 32 + lane] = sp;
    __syncthreads();
    if (tid < 32) {
        float t = 0.f;
#pragma unroll
        for (int ww = 0; ww < 8; ++ww) t += row_ps[ww * 32 + tid];
        row_inv[tid] = 1.0f / t;
    }
    __syncthreads();

    // ---- direct normalized store: wave (mi,ni) -> rows mi*16+kg*4+q, col ni*16+r_a ----
    float* ob = out + ((size_t)b * NN + i0 + mi * 16) * FF + ni * 16;
#pragma unroll
    for (int q = 0; q < 4; ++q) {
        int rr = kg * 4 + q;
        ob[(size_t)rr * FF + r_a] = acc[q] * row_inv[mi * 16 + rr];
    }
}

// ---------------------------------------------------------------------------
extern "C" void kernel_launch(void* const* d_in, const int* in_sizes, int n_in,
                              void* d_out, int out_size, void* d_ws, size_t ws_size,
                              hipStream_t stream) {
    const float* h   = (const float*)d_in[0];
    const int*   adj = (const int*)d_in[1];
    const float* W   = (const float*)d_in[2];
    const float* a   = (const float*)d_in[3];
    float* out = (float*)d_out;

    short* WhHiT = (short*)d_ws;                          // 4*128*2176 shorts = 2.13 MB
    short* WhLoT = WhHiT + (size_t)BB * FF * NP;          // 2.13 MB
    float* f1 = (float*)(WhLoT + (size_t)BB * FF * NP);   // 32 KB
    float* f2 = f1 + (size_t)BB * NN;                     // 32 KB
    u32* adjp = (u32*)(f2 + (size_t)BB * NN);             // 512 KB (total ~4.83 MB, proven r10)

    k_wh<<<(BB * NN) / 16, 256, 0, stream>>>(h, W, a, adj, WhHiT, WhLoT, f1, f2, adjp);
    k_attn<<<BB * (NN / 32), 1024, 0, stream>>>(WhHiT, WhLoT, adjp, f1, f2, out);
}

// Round 15
// 137.721 us; speedup vs baseline: 1.2655x; 1.0824x over previous
//
#include <hip/hip_runtime.h>

#define BB 4
#define NN 2048
#define FF 128
#define NP 2176  // padded WhT row stride (shorts)
#define ALPHA 0.2f
#define SHIFT_C 16.0f  // exp(x-16): x=LR(f1+f2) bounded ~|10|; masked -> p=0 via bit-multiply

typedef short bf16x8 __attribute__((ext_vector_type(8)));
typedef float f32x4 __attribute__((ext_vector_type(4)));
typedef unsigned u32;

__device__ inline short f2bf(float f) {  // RNE float -> bf16 bits
    union { float f; unsigned u; } v; v.f = f;
    unsigned r = (v.u + 0x7FFFu + ((v.u >> 16) & 1u)) >> 16;
    return (short)r;
}
__device__ inline float bf2f(short s) {
    union { float f; unsigned u; } v;
    v.u = ((unsigned)(unsigned short)s) << 16;
    return v.f;
}

// async 16B global->LDS (gfx950); HW writes lds_base + lane*16
__device__ inline void cp16(const void* g, void* l) {
    __builtin_amdgcn_global_load_lds(
        (const __attribute__((address_space(1))) u32*)g,
        (__attribute__((address_space(3))) u32*)l, 16, 0, 0);
}

// ---------------------------------------------------------------------------
// k_wh: round-14 body (passed) with de-serialized adj-pack: thread g owns
// word (row=g>>6, wd=g&63): 8 independent int4 loads -> 32 bits. Everything
// else verbatim (fused f12 + fp32 GEMM + split-bf16 NP-strided store).
// ---------------------------------------------------------------------------
__global__ __launch_bounds__(256) void k_wh(const float* __restrict__ h,
                                            const float* __restrict__ W,
                                            const float* __restrict__ a,
                                            const int* __restrict__ adj,
                                            short* __restrict__ WhHiT,
                                            short* __restrict__ WhLoT,
                                            float* __restrict__ f1,
                                            float* __restrict__ f2,
                                            u32* __restrict__ adjp) {
    __shared__ float Wa[2 * FF];
    __shared__ float hs[16 * 128];  // 8 KB
    int tid = threadIdx.x;
    int r0 = blockIdx.x * 16;

    {
        int fin = tid & 127;
        const float* av = (tid < 128) ? a : (a + FF);
        const float* wr = W + (size_t)fin * FF;
        float s = 0.f;
        for (int o = 0; o < FF; o += 4) {
            float4 wv = *(const float4*)(wr + o);
            float4 avv = *(const float4*)(av + o);
            s += wv.x * avv.x + wv.y * avv.y + wv.z * avv.z + wv.w * avv.w;
        }
        Wa[(tid < 128 ? 0 : FF) + fin] = s;
    }
    {
        const float4* src = (const float4*)(h + (size_t)r0 * FF);
        float4* dst = (float4*)hs;
        dst[tid] = src[tid];
        dst[256 + tid] = src[256 + tid];
    }
    // de-serialized adj pack: 512 blocks * 256 thr = 131072 = 2048 rows * 64 words
    {
        int g = blockIdx.x * 256 + tid;
        int row = g >> 6, wd = g & 63;
        const int4* ar = (const int4*)(adj + (size_t)row * NN + wd * 32);
        u32 word = 0;
#pragma unroll
        for (int q = 0; q < 8; ++q) {
            int4 v = ar[q];
            word |= (u32)(v.x > 0) << (q * 4);
            word |= (u32)(v.y > 0) << (q * 4 + 1);
            word |= (u32)(v.z > 0) << (q * 4 + 2);
            word |= (u32)(v.w > 0) << (q * 4 + 3);
        }
        adjp[row * 64 + wd] = word;
    }
    __syncthreads();

    {
        int w = tid >> 6, lane = tid & 63;
        float wa1_0 = Wa[lane], wa1_1 = Wa[lane + 64];
        float wa2_0 = Wa[FF + lane], wa2_1 = Wa[FF + lane + 64];
        for (int rr = 0; rr < 4; ++rr) {
            int rloc = w * 4 + rr;
            int row = r0 + rloc;
            float x0 = hs[rloc * FF + lane], x1 = hs[rloc * FF + lane + 64];
            float s1 = x0 * wa1_0 + x1 * wa1_1;
            float s2 = x0 * wa2_0 + x1 * wa2_1;
#pragma unroll
            for (int m = 32; m >= 1; m >>= 1) {
                s1 += __shfl_xor(s1, m, 64);
                s2 += __shfl_xor(s2, m, 64);
            }
            if (lane == 0) { f1[row] = s1; f2[row] = s2; }
        }
    }

    int f4 = (tid & 31) * 4;
    int rg = tid >> 5;  // 0..7
    float acc[2][4];
#pragma unroll
    for (int rr = 0; rr < 2; ++rr)
#pragma unroll
        for (int cc = 0; cc < 4; ++cc) acc[rr][cc] = 0.f;

    for (int k0 = 0; k0 < FF; k0 += 4) {
        float4 wv[4];
#pragma unroll
        for (int kk = 0; kk < 4; ++kk)
            wv[kk] = *(const float4*)(W + (size_t)(k0 + kk) * FF + f4);
        float4 hv[2];
#pragma unroll
        for (int rr = 0; rr < 2; ++rr)
            hv[rr] = *(const float4*)(hs + (rg * 2 + rr) * FF + k0);
#pragma unroll
        for (int rr = 0; rr < 2; ++rr) {
            float hk[4] = {hv[rr].x, hv[rr].y, hv[rr].z, hv[rr].w};
#pragma unroll
            for (int kk = 0; kk < 4; ++kk) {
                acc[rr][0] += hk[kk] * wv[kk].x;
                acc[rr][1] += hk[kk] * wv[kk].y;
                acc[rr][2] += hk[kk] * wv[kk].z;
                acc[rr][3] += hk[kk] * wv[kk].w;
            }
        }
    }
    int rloc = r0 + rg * 2;
    int b = rloc >> 11;
    int j = rloc & (NN - 1);  // even
#pragma unroll
    for (int cc = 0; cc < 4; ++cc) {
        float v0 = acc[0][cc], v1 = acc[1][cc];
        short h0 = f2bf(v0), h1 = f2bf(v1);
        short l0 = f2bf(v0 - bf2f(h0)), l1 = f2bf(v1 - bf2f(h1));
        size_t off = (size_t)(b * FF + f4 + cc) * NP + j;
        *(short2*)(WhHiT + off) = make_short2(h0, h1);
        *(short2*)(WhLoT + off) = make_short2(l0, l1);
    }
}

// ---------------------------------------------------------------------------
// k_attn flash-v5: fo-split blocks (32 rows x 64 fo), grid 512 x 512 thr
// (8 waves; 2 independent blocks/CU). 32 periods of 2 steps per barrier:
// period p computes steps 2p,2p+1 from parity-own B/A buffers while staging
// period p+1 (2 cp16 + A-build) into parity-other. Per wave per period:
// 6 ds_read_b128 + 4 MFMA. Direct normalized store.
// ---------------------------------------------------------------------------
__global__ __launch_bounds__(512, 4) void k_attn(const short* __restrict__ WhHiT,
                                                 const short* __restrict__ WhLoT,
                                                 const u32* __restrict__ adjp,
                                                 const float* __restrict__ f1,
                                                 const float* __restrict__ f2,
                                                 float* __restrict__ out) {
    __shared__ __align__(16) char lds[44160];
    char* Bb = lds;                           // 4 x 8192 (per step-buf: hi 4K + lo 4K)
    char* Ab = lds + 32768;                   // 4 x 2560
    float* row_ps = (float*)(lds + 43008);    // [8][32]
    float* row_inv = (float*)(lds + 44032);   // [32]

    int tid = threadIdx.x;
    int w = tid >> 6, lane = tid & 63;        // w 0..7
    int blk = blockIdx.x;
    int b = blk >> 7;
    int tile = (blk >> 1) & 63;
    int half = blk & 1;
    int i0 = tile * 32;

    int r_a = lane & 15, kg = lane >> 4;
    int mi = w >> 2, ni = w & 3;

    // A-build role: thread -> (row rb, j-pair jp); all 512 threads
    int rb = tid & 31;
    int jp = (tid >> 5) & 15;
    float f1i = f1[b * NN + i0 + rb];
    const u32* aprow = adjp + (size_t)(i0 + rb) * 64;
    const float* f2b = f2 + b * NN;
    int aoff = (rb >> 4) * 1280 + (rb & 15) * 80 + jp * 4;

    // B-stage role: waves 0-3 hi, 4-7 lo; 16 fo each within block's half
    int isLo = w >> 2;
    int sub = w & 3;
    int fo_s = half * 64 + sub * 16 + (lane >> 2);
    int oc_s = lane & 3;
    const short* gB = (isLo ? WhLoT : WhHiT) + (size_t)(b * FF + fo_s) * NP + oc_s * 8;
    int bB = isLo * 4096 + sub * 1024;  // wave-uniform base within one 8KB step-buf

    f32x4 acc = {0.f, 0.f, 0.f, 0.f};
    float sp = 0.f;

    // ---- prologue: stage+build period 0; prefetch period-1 regs ----
    cp16(gB, Bb + bB);
    cp16(gB + 32, Bb + 8192 + bB);
    {
        float2 qa = *(const float2*)(f2b + jp * 2);
        float2 qb = *(const float2*)(f2b + 32 + jp * 2);
        u32 wa = aprow[0], wb = aprow[1];
        float x;
        x = f1i + qa.x; x = fmaxf(x, ALPHA * x);
        float p00 = __expf(x - SHIFT_C) * (float)((wa >> (jp * 2)) & 1u);
        x = f1i + qa.y; x = fmaxf(x, ALPHA * x);
        float p01 = __expf(x - SHIFT_C) * (float)((wa >> (jp * 2 + 1)) & 1u);
        x = f1i + qb.x; x = fmaxf(x, ALPHA * x);
        float p10 = __expf(x - SHIFT_C) * (float)((wb >> (jp * 2)) & 1u);
        x = f1i + qb.y; x = fmaxf(x, ALPHA * x);
        float p11 = __expf(x - SHIFT_C) * (float)((wb >> (jp * 2 + 1)) & 1u);
        sp += p00 + p01 + p10 + p11;
        union { float f; u32 u; } u0, u1;
        u0.f = p00; u1.f = p01;
        *(u32*)(Ab + aoff) = ((u0.u + 0x8000u) >> 16) | (((u1.u + 0x8000u) >> 16) << 16);
        u0.f = p10; u1.f = p11;
        *(u32*)(Ab + 2560 + aoff) = ((u0.u + 0x8000u) >> 16) | (((u1.u + 0x8000u) >> 16) << 16);
    }
    float2 pfa = *(const float2*)(f2b + 64 + jp * 2);
    float2 pfb = *(const float2*)(f2b + 96 + jp * 2);
    u32 pwa = aprow[2], pwb = aprow[3];
    __syncthreads();

    for (int p = 0; p < 32; ++p) {
        int par = p & 1, opar = par ^ 1;
        // stage B for period p+1 (wrapped at p=31; wrap unread)
        {
            int j0n = ((2 * p + 2) & 63) * 32;
            int j1n = ((2 * p + 3) & 63) * 32;
            cp16(gB + j0n, Bb + opar * 16384 + bB);
            cp16(gB + j1n, Bb + opar * 16384 + 8192 + bB);
        }
        // build A for period p+1 from prefetched regs
        {
            float x;
            x = f1i + pfa.x; x = fmaxf(x, ALPHA * x);
            float p00 = __expf(x - SHIFT_C) * (float)((pwa >> (jp * 2)) & 1u);
            x = f1i + pfa.y; x = fmaxf(x, ALPHA * x);
            float p01 = __expf(x - SHIFT_C) * (float)((pwa >> (jp * 2 + 1)) & 1u);
            x = f1i + pfb.x; x = fmaxf(x, ALPHA * x);
            float p10 = __expf(x - SHIFT_C) * (float)((pwb >> (jp * 2)) & 1u);
            x = f1i + pfb.y; x = fmaxf(x, ALPHA * x);
            float p11 = __expf(x - SHIFT_C) * (float)((pwb >> (jp * 2 + 1)) & 1u);
            if (p < 31) sp += p00 + p01 + p10 + p11;  // exclude wrapped rebuild
            union { float f; u32 u; } u0, u1;
            u0.f = p00; u1.f = p01;
            *(u32*)(Ab + opar * 5120 + aoff) =
                ((u0.u + 0x8000u) >> 16) | (((u1.u + 0x8000u) >> 16) << 16);
            u0.f = p10; u1.f = p11;
            *(u32*)(Ab + opar * 5120 + 2560 + aoff) =
                ((u0.u + 0x8000u) >> 16) | (((u1.u + 0x8000u) >> 16) << 16);
        }
        // prefetch regs for period p+2 (wrapped)
        {
            int s0 = (2 * p + 4) & 63, s1 = (2 * p + 5) & 63;
            pfa = *(const float2*)(f2b + s0 * 32 + jp * 2);
            pfb = *(const float2*)(f2b + s1 * 32 + jp * 2);
            pwa = aprow[s0]; pwb = aprow[s1];
        }
        // compute steps 2p, 2p+1 from parity-own buffers
        {
            char* bbase = Bb + par * 16384;
            char* abase = Ab + par * 5120;
            int boff = (ni * 16 + r_a) * 64 + kg * 16;
            bf16x8 af0 = *(const bf16x8*)(abase + mi * 1280 + r_a * 80 + kg * 16);
            bf16x8 b0h = *(const bf16x8*)(bbase + boff);
            bf16x8 b0l = *(const bf16x8*)(bbase + 4096 + boff);
            acc = __builtin_amdgcn_mfma_f32_16x16x32_bf16(af0, b0h, acc, 0, 0, 0);
            acc = __builtin_amdgcn_mfma_f32_16x16x32_bf16(af0, b0l, acc, 0, 0, 0);
            bf16x8 af1 = *(const bf16x8*)(abase + 2560 + mi * 1280 + r_a * 80 + kg * 16);
            bf16x8 b1h = *(const bf16x8*)(bbase + 8192 + boff);
            bf16x8 b1l = *(const bf16x8*)(bbase + 8192 + 4096 + boff);
            acc = __builtin_amdgcn_mfma_f32_16x16x32_bf16(af1, b1h, acc, 0, 0, 0);
            acc = __builtin_amdgcn_mfma_f32_16x16x32_bf16(af1, b1l, acc, 0, 0, 0);
        }
        __syncthreads();
    }

    // ---- row sums ----
    sp += __shfl_xor(sp, 32, 64);              // jp 2w <-> 2w+1, same row rb
    if (lane < 32) row_ps[w * 32 + lane] = sp;
    __syncthreads();
    if (tid < 32) {
        float t = 0.f;
#pragma unroll
        for (int ww = 0; ww < 8; ++ww) t += row_ps[ww * 32 + tid];
        row_inv[tid] = 1.0f / t;
    }
    __syncthreads();

    // ---- direct normalized store: rows i0+mi*16+kg*4+q, col half*64+ni*16+r_a ----
    float* ob = out + ((size_t)b * NN + i0 + mi * 16) * FF + half * 64 + ni * 16;
#pragma unroll
    for (int q = 0; q < 4; ++q) {
        int rr = kg * 4 + q;
        ob[(size_t)rr * FF + r_a] = acc[q] * row_inv[mi * 16 + rr];
    }
}

// ---------------------------------------------------------------------------
extern "C" void kernel_launch(void* const* d_in, const int* in_sizes, int n_in,
                              void* d_out, int out_size, void* d_ws, size_t ws_size,
                              hipStream_t stream) {
    const float* h   = (const float*)d_in[0];
    const int*   adj = (const int*)d_in[1];
    const float* W   = (const float*)d_in[2];
    const float* a   = (const float*)d_in[3];
    float* out = (float*)d_out;

    short* WhHiT = (short*)d_ws;                          // 2.13 MB
    short* WhLoT = WhHiT + (size_t)BB * FF * NP;          // 2.13 MB
    float* f1 = (float*)(WhLoT + (size_t)BB * FF * NP);   // 32 KB
    float* f2 = f1 + (size_t)BB * NN;                     // 32 KB
    u32* adjp = (u32*)(f2 + (size_t)BB * NN);             // 512 KB (total ~4.83 MB, proven)

    k_wh<<<(BB * NN) / 16, 256, 0, stream>>>(h, W, a, adj, WhHiT, WhLoT, f1, f2, adjp);
    k_attn<<<512, 512, 0, stream>>>(WhHiT, WhLoT, adjp, f1, f2, out);
}